// Round 2
// baseline (11999.140 us; speedup 1.0000x reference)
//
#include <hip/hip_runtime.h>
#include <cstdint>
#include <cmath>

// Problem dims
#define NB 512
#define NN 100
#define NE 256
#define NHID 1024
#define NL 6
#define NH 8
#define NDH 32

static constexpr float SQRT_DH = 5.656854249492380195206754896838f; // sqrt(32)
static constexpr float NEGV = -1e9f;

// ---- workspace layout (in floats) ----
static constexpr size_t WS_A   = 0;          // h / nodes_emb
static constexpr size_t WS_B1  = 13107200;   // q / oWo / ffn_tmp(lo) / dk
static constexpr size_t WS_B2  = 26214400;   // k / ffn_tmp(hi)       / dv
static constexpr size_t WS_B3  = 39321600;   // v / ffn2_out / kq / Qall3
static constexpr size_t WS_B4  = 52428800;   // attn_o / kqT
static constexpr size_t WS_G   = 65536000;   // graph_emb   [512,256]
static constexpr size_t WS_QB  = 65667072;   // qbase1      [512,256]
static constexpr size_t WS_TC  = 65798144;   // tcom        [256]
static constexpr size_t WS_WPO = 65798400;   // Wp@Wo^T     [256,256]
static constexpr size_t WS_NLL = 65863936;   // nll partials[512]

__device__ __forceinline__ float wave_sum64(float v) {
#pragma unroll
  for (int o = 32; o; o >>= 1) v += __shfl_xor(v, o, 64);
  return v;
}
__device__ __forceinline__ double wave_sum64d(double v) {
#pragma unroll
  for (int o = 32; o; o >>= 1) v += __shfl_xor(v, o, 64);
  return v;
}
__device__ __forceinline__ float wave_max64(float v) {
#pragma unroll
  for (int o = 32; o; o >>= 1) v = fmaxf(v, __shfl_xor(v, o, 64));
  return v;
}

// ---------------- embed: h = x @ Win + bin ----------------
__global__ __launch_bounds__(256) void embed_kernel(
    const float* __restrict__ x, const float* __restrict__ win,
    const float* __restrict__ bin, float* __restrict__ h) {
  int i = blockIdx.x * 256 + threadIdx.x;      // over 51200*64 float4s
  int bn = i >> 6, e4 = i & 63;
  float x0 = x[bn * 2], x1 = x[bn * 2 + 1];
  float4 w0 = ((const float4*)win)[e4];
  float4 w1 = ((const float4*)win)[64 + e4];
  float4 bb = ((const float4*)bin)[e4];
  float4 r;
  r.x = x0 * w0.x + x1 * w1.x + bb.x;
  r.y = x0 * w0.y + x1 * w1.y + bb.y;
  r.z = x0 * w0.z + x1 * w1.z + bb.z;
  r.w = x0 * w0.w + x1 * w1.w + bb.w;
  ((float4*)h)[i] = r;
}

// ---------------- fp32 tiled GEMM: C = A[M,K] @ W[K,N](ldw) ----------------
template <bool BIAS, bool RELU, bool ACCUM>
__global__ __launch_bounds__(256) void gemm_f32(
    const float* __restrict__ A, const float* __restrict__ W,
    const float* __restrict__ bias, float* __restrict__ C,
    int M, int N, int K, int ldw, int ldc) {
  __shared__ __align__(16) float As[16][132];  // A^T [k][m], padded
  __shared__ __align__(16) float Bs[16][128];
  const int t = threadIdx.x;
  const int bm = blockIdx.x * 128;
  const int bn = blockIdx.y * 128;
  const int tx = t & 15, ty = t >> 4;
  float acc[8][8];
#pragma unroll
  for (int i = 0; i < 8; ++i)
#pragma unroll
    for (int j = 0; j < 8; ++j) acc[i][j] = 0.f;

  const int am = t >> 2;          // 0..63
  const int ak = (t & 3) << 2;    // 0,4,8,12
  const int bn4 = (t & 31) << 2;  // 0..124
  const int bk = t >> 5;          // 0..7

  for (int kt = 0; kt < K; kt += 16) {
#pragma unroll
    for (int i = 0; i < 2; ++i) {
      float4 av = *(const float4*)&A[(size_t)(bm + am + 64 * i) * K + kt + ak];
      As[ak + 0][am + 64 * i] = av.x;
      As[ak + 1][am + 64 * i] = av.y;
      As[ak + 2][am + 64 * i] = av.z;
      As[ak + 3][am + 64 * i] = av.w;
      float4 bv = *(const float4*)&W[(size_t)(kt + bk + 8 * i) * ldw + bn + bn4];
      *(float4*)&Bs[bk + 8 * i][bn4] = bv;
    }
    __syncthreads();
#pragma unroll
    for (int k = 0; k < 16; ++k) {
      float a[8], bb[8];
      *(float4*)(a) = *(const float4*)&As[k][ty * 4];
      *(float4*)(a + 4) = *(const float4*)&As[k][64 + ty * 4];
      *(float4*)(bb) = *(const float4*)&Bs[k][tx * 4];
      *(float4*)(bb + 4) = *(const float4*)&Bs[k][64 + tx * 4];
#pragma unroll
      for (int i = 0; i < 8; ++i)
#pragma unroll
        for (int j = 0; j < 8; ++j) acc[i][j] += a[i] * bb[j];
    }
    __syncthreads();
  }
#pragma unroll
  for (int i = 0; i < 8; ++i) {
    int row = bm + ((i < 4) ? (ty * 4 + i) : (64 + ty * 4 + i - 4));
    size_t rb = (size_t)row * ldc;
#pragma unroll
    for (int jh = 0; jh < 2; ++jh) {
      int col = bn + jh * 64 + tx * 4;
      float4 v;
      v.x = acc[i][jh * 4 + 0];
      v.y = acc[i][jh * 4 + 1];
      v.z = acc[i][jh * 4 + 2];
      v.w = acc[i][jh * 4 + 3];
      if (BIAS) {
        v.x += bias[col]; v.y += bias[col + 1];
        v.z += bias[col + 2]; v.w += bias[col + 3];
      }
      if (RELU) {
        v.x = fmaxf(v.x, 0.f); v.y = fmaxf(v.y, 0.f);
        v.z = fmaxf(v.z, 0.f); v.w = fmaxf(v.w, 0.f);
      }
      if (ACCUM) {
        float4 o = *(const float4*)&C[rb + col];
        v.x += o.x; v.y += o.y; v.z += o.z; v.w += o.w;
      }
      *(float4*)&C[rb + col] = v;
    }
  }
}

// ---- f64-accumulated small GEMM: C[M,256] = A[M,256] @ W[256,256], 16 rows/blk ----
__global__ __launch_bounds__(256) void kq_gemm(
    const float* __restrict__ A, const float* __restrict__ W,
    float* __restrict__ C) {
  __shared__ float rows[16][256];
  const int t = threadIdx.x;
  const int r0 = blockIdx.x * 16;
#pragma unroll
  for (int r = 0; r < 16; ++r) rows[r][t] = A[(size_t)(r0 + r) * 256 + t];
  __syncthreads();
  double acc[16];
#pragma unroll
  for (int r = 0; r < 16; ++r) acc[r] = 0.0;
  for (int d = 0; d < 256; ++d) {
    double wd = (double)W[d * 256 + t];
#pragma unroll
    for (int r = 0; r < 16; ++r) acc[r] += (double)rows[r][d] * wd;
  }
#pragma unroll
  for (int r = 0; r < 16; ++r)
    C[(size_t)(r0 + r) * 256 + t] = (float)acc[r];
}

// ---------------- encoder attention: one block per (b,h) ----------------
__global__ __launch_bounds__(256) void enc_attn(
    const float* __restrict__ q, const float* __restrict__ k,
    const float* __restrict__ v, float* __restrict__ o) {
  const int bh = blockIdx.x;
  const int b = bh >> 3, h = bh & 7;
  __shared__ float qs[100][33], ks[100][33], vs[100][33];
  __shared__ float arow[4][100];
  const int t = threadIdx.x;
  const int lane = t & 63, w = t >> 6;
  const size_t base = (size_t)b * (NN * NE) + h * NDH;
  const int d0 = t & 31, n0 = t >> 5;
  for (int i = 0; i < 13; ++i) {
    int n = n0 + 8 * i;
    if (n < 100) {
      size_t gix = base + (size_t)n * NE + d0;
      qs[n][d0] = q[gix];
      ks[n][d0] = k[gix];
      vs[n][d0] = v[gix];
    }
  }
  __syncthreads();
  for (int i = w; i < 100; i += 4) {
    float s1 = 0.f, s2 = 0.f;
#pragma unroll
    for (int d = 0; d < 32; ++d) {
      float qv = qs[i][d];
      s1 += qv * ks[lane][d];
      if (lane < 36) s2 += qv * ks[lane + 64][d];
    }
    s1 /= SQRT_DH;
    s2 /= SQRT_DH;
    float mx = wave_max64(fmaxf(s1, (lane < 36) ? s2 : -3.4e38f));
    float e1 = expf(s1 - mx);
    float e2 = (lane < 36) ? expf(s2 - mx) : 0.f;
    float sm = wave_sum64(e1 + e2);
    arow[w][lane] = e1 / sm;
    if (lane < 36) arow[w][lane + 64] = e2 / sm;
    const int dd = lane & 31, half = lane >> 5;
    float accum = 0.f;
#pragma unroll
    for (int jj = 0; jj < 50; ++jj) {
      int j = half * 50 + jj;
      accum += arow[w][j] * vs[j][dd];
    }
    accum += __shfl_xor(accum, 32, 64);
    if (lane < 32) o[base + (size_t)i * NE + lane] = accum;
  }
}

// ---------------- fused residual + LayerNorm (wave per row) ----------------
__global__ __launch_bounds__(256) void ln_fused(
    const float* __restrict__ x, const float* __restrict__ r,
    const float* __restrict__ s, const float* __restrict__ bta,
    float* __restrict__ out) {
  const int t = threadIdx.x, lane = t & 63, w = t >> 6;
  const size_t row = (size_t)blockIdx.x * 4 + w;
  const size_t off = row * NE + lane * 4;
  float4 xv = *(const float4*)&x[off];
  float4 rv = *(const float4*)&r[off];
  float hx = xv.x + rv.x, hy = xv.y + rv.y, hz = xv.z + rv.z, hw = xv.w + rv.w;
  float sm = wave_sum64(hx + hy + hz + hw);
  float mean = sm * (1.f / 256.f);
  float dx = hx - mean, dy = hy - mean, dz = hz - mean, dw = hw - mean;
  float sq = wave_sum64(dx * dx + dy * dy + dz * dz + dw * dw);
  float var = sq * (1.f / 256.f);
  float rstd = 1.f / sqrtf(var + 1e-5f);
  float4 sv = *(const float4*)&s[lane * 4];
  float4 bv = *(const float4*)&bta[lane * 4];
  float4 ov;
  ov.x = dx * rstd * sv.x + bv.x;
  ov.y = dy * rstd * sv.y + bv.y;
  ov.z = dz * rstd * sv.z + bv.z;
  ov.w = dw * rstd * sv.w + bv.w;
  *(float4*)&out[off] = ov;
}

// ---------------- graph mean (f64 acc) ----------------
__global__ __launch_bounds__(256) void graph_mean(
    const float* __restrict__ h, float* __restrict__ g) {
  int b = blockIdx.x, t = threadIdx.x;
  const float* hb = h + (size_t)b * (NN * NE);
  double acc = 0.0;
  for (int n = 0; n < 100; ++n) acc += (double)hb[n * NE + t];
  g[b * NE + t] = (float)(acc / 100.0);
}

// ---------------- Wpo = Wp @ Wo^T (f64 acc) ----------------
__global__ __launch_bounds__(256) void wpo_kernel(
    const float* __restrict__ Wp, const float* __restrict__ Wo,
    float* __restrict__ Wpo) {
  int d = blockIdx.x, t = threadIdx.x, lane = t & 63, w = t >> 6;
  __shared__ float wpl[256];
  wpl[t] = Wp[d * 256 + t];
  __syncthreads();
  for (int f = w; f < 256; f += 4) {
    float4 wov = *(const float4*)&Wo[f * 256 + lane * 4];
    float4 wpv = *(const float4*)&wpl[lane * 4];
    double p = (double)wov.x * wpv.x + (double)wov.y * wpv.y +
               (double)wov.z * wpv.z + (double)wov.w * wpv.w;
    p = wave_sum64d(p);
    if (lane == 0) Wpo[d * 256 + f] = (float)p;
  }
}

// ---------------- qbase1 = graph @ Wq1 (f64 acc) ----------------
__global__ __launch_bounds__(256) void qbase_kernel(
    const float* __restrict__ g, const float* __restrict__ wq,
    float* __restrict__ qb) {
  int b = blockIdx.x, t = threadIdx.x;
  __shared__ float gl[256];
  gl[t] = g[b * 256 + t];
  __syncthreads();
  double acc = 0.0;
  for (int d = 0; d < 256; ++d) acc += (double)gl[d] * wq[d * 256 + t];
  qb[b * 256 + t] = (float)acc;
}

// ---------------- tcom = token_1 @ Wq2 + token_f @ Wq3 (f64 acc) ----------------
__global__ __launch_bounds__(256) void tcom_kernel(
    const float* __restrict__ t1, const float* __restrict__ tf,
    const float* __restrict__ wq, float* __restrict__ tc) {
  int t = threadIdx.x;
  __shared__ float a1[256], a2[256];
  a1[t] = t1[t];
  a2[t] = tf[t];
  __syncthreads();
  double acc = 0.0;
  for (int d = 0; d < 256; ++d) {
    acc += (double)a1[d] * wq[(256 + d) * 256 + t];
    acc += (double)a2[d] * wq[(512 + d) * 256 + t];
  }
  tc[t] = (float)acc;
}

// ---------------- per-batch transpose kq[m,f] -> kqT[f,m] ----------------
__global__ __launch_bounds__(256) void kq_transpose(
    const float* __restrict__ kq, float* __restrict__ kqT) {
  int b = blockIdx.x, t = threadIdx.x;
  const float* src = kq + (size_t)b * 25600;
  float* dst = kqT + (size_t)b * 25600;
  for (int i = t; i < 25600; i += 256) {
    int f = i / 100, m = i - f * 100;
    dst[i] = src[m * 256 + f];
  }
}

// ---------------- persistent greedy decode: one block per batch ----------------
__global__ __launch_bounds__(256) void decode_kernel(
    const float* __restrict__ nodes, const float* __restrict__ dk,
    const float* __restrict__ dv, const float* __restrict__ kqT,
    const float* __restrict__ q3, const float* __restrict__ qb,
    const float* __restrict__ tc, const float* __restrict__ wq2,
    const int* __restrict__ target, float* __restrict__ out,
    float* __restrict__ nllp) {
  const int b = blockIdx.x, t = threadIdx.x;
  const int lane = t & 63, w = t >> 6;
  __shared__ __align__(16) float vs[25600];
  __shared__ __align__(16) float qh[256];
  __shared__ float qfix[256], noderow[256], g[256];
  __shared__ float sc[800];
  __shared__ double lpartd[256];
  __shared__ float logits[100], pr[100], mask[100];
  __shared__ int idx_sh;

  const float* dvb = dv + (size_t)b * 25600;
  for (int i = t; i < 6400; i += 256)
    ((float4*)vs)[i] = ((const float4*)dvb)[i];
  if (t < 100) mask[t] = 0.f;
  qh[t] = qb[b * 256 + t] + tc[t];
  __syncthreads();

  const float* kb = dk + (size_t)b * 25600;
  const float* kqb = kqT + (size_t)b * 25600;
  const float* q3b = q3 + (size_t)b * 25600;
  float nll_acc = 0.f;

  for (int step = 0; step < 100; ++step) {
    // scores sc[h,n] = f32(f64 dot(qh[h,:], k[n,h,:])) / sqrt(DH), masked
    for (int p = t; p < 800; p += 256) {
      int hh = p / 100;
      int n = p - hh * 100;
      const float* kr = kb + n * 256 + hh * 32;
      const float* qr = qh + hh * 32;
      double s = 0.0;
#pragma unroll
      for (int d4 = 0; d4 < 8; ++d4) {
        float4 kv = *(const float4*)(kr + d4 * 4);
        float4 qv = *(const float4*)(qr + d4 * 4);
        s += (double)qv.x * kv.x + (double)qv.y * kv.y +
             (double)qv.z * kv.z + (double)qv.w * kv.w;
      }
      float sf = (float)s / SQRT_DH;
      if (mask[n] > 0.f) sf = NEGV;
      sc[p] = sf;
    }
    __syncthreads();
    // softmax over n per head (wave per 2 heads)
    for (int hh = w; hh < 8; hh += 4) {
      float v1 = sc[hh * 100 + lane];
      float v2 = (lane < 36) ? sc[hh * 100 + 64 + lane] : -3.4e38f;
      float mx = wave_max64(fmaxf(v1, v2));
      float e1 = expf(v1 - mx);
      float e2 = (lane < 36) ? expf(v2 - mx) : 0.f;
      float sm = wave_sum64(e1 + e2);
      sc[hh * 100 + lane] = e1 / sm;
      if (lane < 36) sc[hh * 100 + 64 + lane] = e2 / sm;
    }
    __syncthreads();
    // g[e] = sum_n a[h,n] * v[n,e]
    {
      const int hh = t >> 5;
      const float* ar = sc + hh * 100;
      float acc = 0.f;
#pragma unroll 4
      for (int n = 0; n < 100; ++n) acc += ar[n] * vs[n * 256 + t];
      g[t] = acc;
    }
    __syncthreads();
    // logits[m] = 10*tanh(f32(f64 dot(g, kqT[:,m])) / 16), masked
    {
      double part = 0.0;
      if (t < 200) {
        int m = (t < 100) ? t : (t - 100);
        int jh = (t < 100) ? 0 : 1;
        const float* kq = kqb + jh * 12800 + m;
        const float* gg = g + jh * 128;
#pragma unroll 16
        for (int f = 0; f < 128; ++f) part += (double)gg[f] * kq[f * 100];
      }
      lpartd[t] = part;
    }
    __syncthreads();
    if (t < 100) {
      double dot = lpartd[t] + lpartd[t + 100];
      float dotf = (float)dot;
      float lg = 10.f * tanhf(dotf * 0.0625f);
      if (mask[t] > 0.f) lg = NEGV;
      logits[t] = lg;
    }
    __syncthreads();
    // softmax + argmax on wave 0, write prob row
    if (w == 0) {
      float v1 = logits[lane];
      float v2 = (lane < 36) ? logits[64 + lane] : -3.4e38f;
      float mx = wave_max64(fmaxf(v1, v2));
      float e1 = expf(v1 - mx);
      float e2 = (lane < 36) ? expf(v2 - mx) : 0.f;
      float sm = wave_sum64(e1 + e2);
      float p1 = e1 / sm;
      float p2 = (lane < 36) ? e2 / sm : 0.f;
      float* orow = out + (size_t)b * 10000 + step * 100;
      orow[lane] = p1;
      pr[lane] = p1;
      if (lane < 36) {
        orow[64 + lane] = p2;
        pr[64 + lane] = p2;
      }
      float val = p1;
      int id = lane;
      if (lane < 36 && p2 > val) { val = p2; id = 64 + lane; }
#pragma unroll
      for (int o = 32; o; o >>= 1) {
        float ov = __shfl_xor(val, o, 64);
        int oi = __shfl_xor(id, o, 64);
        if (ov > val || (ov == val && oi < id)) { val = ov; id = oi; }
      }
      if (lane == 0) idx_sh = id;
    }
    __syncthreads();
    const int idx = idx_sh;
    if (t == 0) {
      mask[idx] = 1.f;
      int tgt = target[b * 100 + step];
      nll_acc -= logf(pr[tgt] + 1e-9f);
      out[5120000 + b * 100 + step] = (float)idx;
    }
    if (step == 0) {
      // qfix = qbase1 + nodes[idx0] @ Wq2  (start embedding fixed hereafter)
      noderow[t] = nodes[(size_t)b * 25600 + idx * 256 + t];
      __syncthreads();
      double s2 = 0.0;
      for (int d = 0; d < 256; ++d) s2 += (double)noderow[d] * wq2[d * 256 + t];
      qfix[t] = qb[b * 256 + t] + (float)s2;
    }
    __syncthreads();
    qh[t] = qfix[t] + q3b[idx * 256 + t];
    __syncthreads();
  }
  if (t == 0) nllp[b] = nll_acc;
}

// ---------------- final nll reduce ----------------
__global__ __launch_bounds__(256) void nll_final(
    const float* __restrict__ nllp, float* __restrict__ out) {
  int t = threadIdx.x, lane = t & 63, w = t >> 6;
  float v = nllp[t] + nllp[t + 256];
  v = wave_sum64(v);
  __shared__ float r[4];
  if (lane == 0) r[w] = v;
  __syncthreads();
  if (t == 0) out[0] = (r[0] + r[1] + r[2] + r[3]) / 51200.f;
}

extern "C" void kernel_launch(void* const* d_in, const int* in_sizes, int n_in,
                              void* d_out, int out_size, void* d_ws,
                              size_t ws_size, hipStream_t stream) {
  const float* x = (const float*)d_in[0];
  const int* target = (const int*)d_in[1];
  const float* Win = (const float*)d_in[2];
  const float* binp = (const float*)d_in[3];
  const float* Wq = (const float*)d_in[4];
  const float* Wk = (const float*)d_in[5];
  const float* Wv = (const float*)d_in[6];
  const float* Wo = (const float*)d_in[7];
  const float* ln1s = (const float*)d_in[8];
  const float* ln1b = (const float*)d_in[9];
  const float* W1 = (const float*)d_in[10];
  const float* b1 = (const float*)d_in[11];
  const float* W2 = (const float*)d_in[12];
  const float* b2 = (const float*)d_in[13];
  const float* ln2s = (const float*)d_in[14];
  const float* ln2b = (const float*)d_in[15];
  const float* dWq = (const float*)d_in[16];
  const float* dWk = (const float*)d_in[17];
  const float* dWv = (const float*)d_in[18];
  const float* dWo = (const float*)d_in[19];
  const float* dWp = (const float*)d_in[20];
  const float* tok1 = (const float*)d_in[21];
  const float* tokf = (const float*)d_in[22];

  float* ws = (float*)d_ws;
  float* out = (float*)d_out;
  float* A = ws + WS_A;
  float* R1 = ws + WS_B1;
  float* R2 = ws + WS_B2;
  float* R3 = ws + WS_B3;
  float* R4 = ws + WS_B4;
  float* G = ws + WS_G;
  float* QB = ws + WS_QB;
  float* TC = ws + WS_TC;
  float* WPO = ws + WS_WPO;
  float* NLLP = ws + WS_NLL;

  const int M = NB * NN;  // 51200
  dim3 g2(400, 2), g4(400, 4), b256(256);

  // h = x @ Win + bin
  embed_kernel<<<12800, 256, 0, stream>>>(x, Win, binp, A);

  for (int l = 0; l < NL; ++l) {
    const float* wq = Wq + (size_t)l * 65536;
    const float* wk = Wk + (size_t)l * 65536;
    const float* wv = Wv + (size_t)l * 65536;
    const float* wo = Wo + (size_t)l * 65536;
    gemm_f32<false, false, false><<<g2, b256, 0, stream>>>(A, wq, nullptr, R1, M, 256, 256, 256, 256);
    gemm_f32<false, false, false><<<g2, b256, 0, stream>>>(A, wk, nullptr, R2, M, 256, 256, 256, 256);
    gemm_f32<false, false, false><<<g2, b256, 0, stream>>>(A, wv, nullptr, R3, M, 256, 256, 256, 256);
    enc_attn<<<4096, 256, 0, stream>>>(R1, R2, R3, R4);
    gemm_f32<false, false, false><<<g2, b256, 0, stream>>>(R4, wo, nullptr, R1, M, 256, 256, 256, 256);
    ln_fused<<<12800, 256, 0, stream>>>(A, R1, ln1s + l * 256, ln1b + l * 256, A);
    // FFN in 2 chunks of HID=512 (tmp spans R1..R2)
    const float* w1 = W1 + (size_t)l * 262144;
    const float* w2 = W2 + (size_t)l * 262144;
    gemm_f32<true, true, false><<<g4, b256, 0, stream>>>(A, w1, b1 + l * 1024, R1, M, 512, 256, 1024, 512);
    gemm_f32<true, false, false><<<g2, b256, 0, stream>>>(R1, w2, b2 + l * 256, R3, M, 256, 512, 256, 256);
    gemm_f32<true, true, false><<<g4, b256, 0, stream>>>(A, w1 + 512, b1 + l * 1024 + 512, R1, M, 512, 256, 1024, 512);
    gemm_f32<false, false, true><<<g2, b256, 0, stream>>>(R1, w2 + 512 * 256, nullptr, R3, M, 256, 512, 256, 256);
    ln_fused<<<12800, 256, 0, stream>>>(A, R3, ln2s + l * 256, ln2b + l * 256, A);
  }

  // decoder precompute
  graph_mean<<<512, 256, 0, stream>>>(A, G);
  wpo_kernel<<<256, 256, 0, stream>>>(dWp, dWo, WPO);
  qbase_kernel<<<512, 256, 0, stream>>>(G, dWq, QB);
  tcom_kernel<<<1, 256, 0, stream>>>(tok1, tokf, dWq, TC);
  // kq = nodes @ (Wp@Wo^T) -> R3 (f64 acc), transpose to R4
  kq_gemm<<<3200, 256, 0, stream>>>(A, WPO, R3);
  kq_transpose<<<512, 256, 0, stream>>>(R3, R4);
  gemm_f32<false, false, false><<<g2, b256, 0, stream>>>(A, dWk, nullptr, R1, M, 256, 256, 256, 256);
  gemm_f32<false, false, false><<<g2, b256, 0, stream>>>(A, dWv, nullptr, R2, M, 256, 256, 256, 256);
  // Qall3 = nodes @ Wq3 -> R3 (f64 acc; kq no longer needed)
  kq_gemm<<<3200, 256, 0, stream>>>(A, dWq + 512 * 256, R3);

  decode_kernel<<<512, 256, 0, stream>>>(A, R1, R2, R4, R3, QB, TC,
                                         dWq + 256 * 256, target, out, NLLP);
  nll_final<<<1, 256, 0, stream>>>(NLLP, out + 5171200);
}